// Round 1
// 267.222 us; speedup vs baseline: 1.0443x; 1.0443x over previous
//
#include <hip/hip_runtime.h>

#define TPB 256
#define ROWN 8192
#define CMAX 1024   // per-row candidate cap (r12-r18 proven never hit)
#define EPS_TINY 1.1754943508222875e-38f   // np.finfo(np.float32).tiny

__device__ __forceinline__ unsigned rotl32(unsigned x, int r) {
  return (x << r) | (x >> (32 - r));
}

// threefry2x32, key (0,42), partitionable counters: ctr=(0,idx), bits = x0^x1.
// Verified on-device (r11 decode; r12-r18 absmax 0.0).
__device__ __forceinline__ unsigned tf_pxor(unsigned idx) {
  const unsigned ks0 = 0u, ks1 = 42u, ks2 = 0x1BD11BDAu ^ 0u ^ 42u;
  unsigned x0 = ks0;
  unsigned x1 = idx + ks1;
#define TF4(a,b,cc,d) \
  x0 += x1; x1 = rotl32(x1,(a));  x1 ^= x0; \
  x0 += x1; x1 = rotl32(x1,(b));  x1 ^= x0; \
  x0 += x1; x1 = rotl32(x1,(cc)); x1 ^= x0; \
  x0 += x1; x1 = rotl32(x1,(d));  x1 ^= x0;
  TF4(13,15,26,6)   x0 += ks1; x1 += ks2 + 1u;
  TF4(17,29,16,24)  x0 += ks2; x1 += ks0 + 2u;
  TF4(13,15,26,6)   x0 += ks0; x1 += ks1 + 3u;
  TF4(17,29,16,24)  x0 += ks1; x1 += ks2 + 4u;
  TF4(13,15,26,6)   x0 += ks2; x1 += ks0 + 5u;
#undef TF4
  return x0 ^ x1;
}

// EXACT jax gumbel (precise ocml logf) — candidates only, bit-exact.
__device__ __forceinline__ float gumbel_of(unsigned idx) {
  const unsigned bits = tf_pxor(idx);
  float u = __uint_as_float((bits >> 9) | 0x3f800000u) - 1.0f;
  u = u + EPS_TINY;
  u = fmaxf(EPS_TINY, u);
  return -logf(-logf(u));
}

// APPROX gumbel for the filter pass: |err| <= ~2e-4 (proven r15-r18).
__device__ __forceinline__ float approx_gumbel(unsigned bits) {
  float u = __uint_as_float((bits >> 9) | 0x3f800000u) - 1.0f;
  u = u + EPS_TINY;
  u = fmaxf(EPS_TINY, u);
  float t;
  if (u >= 0.75f) {
    const float v = 1.0f - u;   // exact (Sterbenz)
    t = v * (1.0f + v * (0.5f + v * (0.33333334f + v * (0.25f + v * 0.2f))));
  } else {
    t = -0.69314718f * __log2f(u);
  }
  return -0.69314718f * __log2f(t);
}

// =====================================================================
// Kernel 1: one block per (rep, b, e) ROW. grid=2048, 256 thr (4 waves).
// Phase 1 identical per-row math as the 512-block version; phase 2
// dynamics are block-wide (4 chunks of 256). Writes sel[32] per row to ws.
// =====================================================================
__global__ __launch_bounds__(TPB, 8)
void topk_row(const void* __restrict__ scores_raw, int* __restrict__ selws) {
  const int t    = threadIdx.x;
  const int lane = t & 63;
  const int wave = t >> 6;

  // XCD grouping: all 8 rows (4e x 2rep) of input panel b land on one XCD,
  // all co-resident (256 blocks/XCD at 8 blocks/CU) -> 4MB input slice = L2.
  const int i   = blockIdx.x;       // 0..2047
  const int xcd = i & 7;
  const int k   = i >> 3;           // 0..255
  const int e   = k & 3;
  const int q   = k >> 2;           // 0..63
  const int b   = xcd * 32 + (q & 31);
  const int rep = q >> 5;
  const int r   = rep * 1024 + b * 4 + e;
  const unsigned gbase = (unsigned)r * (unsigned)ROWN;

  __shared__ int   candIdx[CMAX];     // 4 KB
  __shared__ float redM[4];
  __shared__ float redZ[4];
  __shared__ int   wtot[13][4];
  __shared__ float bV[2][4];
  __shared__ int   bI[2][4];
  __shared__ int   sel[32];
  __shared__ int   f32flag;

  // ---- input dtype autodetect (4 KB prefix; proven r11-r18) ----
  if (t == 0) f32flag = 0;
  __syncthreads();
  {
    const unsigned* w = (const unsigned*)scores_raw;
    bool bad = false;
#pragma unroll
    for (int p = 0; p < 4; ++p) {
      const unsigned x = w[t + 256 * p];
      const float flo = __uint_as_float((x & 0xFFFFu) << 16);
      const float fhi = __uint_as_float(x & 0xFFFF0000u);
      if (!(fabsf(flo) <= 16.0f) || !(fabsf(fhi) <= 16.0f)) bad = true;
    }
    if (bad) f32flag = 1;
  }
  __syncthreads();
  const bool in_f32 = (f32flag != 0);

  // ================= phase 1: gen -> theta -> compact (single row) ======
  const size_t ebase0 = ((size_t)b * ROWN + (size_t)t) * 4 + (size_t)e;
  float f[32];
  if (in_f32) {
    const float* sp = (const float*)scores_raw;
#pragma unroll
    for (int j = 0; j < 32; ++j)
      f[j] = sp[ebase0 + (size_t)(256 * j) * 4]
           + approx_gumbel(tf_pxor(gbase + (unsigned)(t + 256 * j)));
  } else {
    const unsigned short* sp = (const unsigned short*)scores_raw;
#pragma unroll
    for (int j = 0; j < 32; ++j)
      f[j] = __uint_as_float(((unsigned)sp[ebase0 + (size_t)(256 * j) * 4]) << 16)
           + approx_gumbel(tf_pxor(gbase + (unsigned)(t + 256 * j)));
  }

  // block max
  float m = f[0];
#pragma unroll
  for (int j = 1; j < 32; ++j) m = fmaxf(m, f[j]);
#pragma unroll
  for (int off = 32; off >= 1; off >>= 1) m = fmaxf(m, __shfl_xor(m, off));
  if (lane == 0) redM[wave] = m;
  __syncthreads();
  m = fmaxf(fmaxf(redM[0], redM[1]), fmaxf(redM[2], redM[3]));

  // bisect theta33 (12 iters, resolution 25/4096 ~ 6e-3)
  float lo = m - 25.0f, hi = m;
#pragma unroll 1
  for (int itb = 0; itb < 12; ++itb) {
    const float mid = 0.5f * (lo + hi);
    int c = 0;
#pragma unroll
    for (int j = 0; j < 32; ++j) c += (f[j] > mid) ? 1 : 0;
#pragma unroll
    for (int off = 32; off >= 1; off >>= 1) c += __shfl_xor(c, off);
    if (lane == 0) wtot[itb][wave] = c;
    __syncthreads();
    const int tot = wtot[itb][0] + wtot[itb][1] + wtot[itb][2] + wtot[itb][3];
    if (tot >= 33) lo = mid; else hi = mid;
  }
  const float theta = lo - 2.34f;   // superset proof margin (r12-r18)

  // compact candidate indices (deterministic prefix order)
  int cj = 0;
#pragma unroll
  for (int j = 0; j < 32; ++j) cj += (f[j] > theta) ? 1 : 0;
  int incv = cj;
#pragma unroll
  for (int off = 1; off < 64; off <<= 1) {
    const int v = __shfl_up(incv, off);
    if (lane >= off) incv += v;
  }
  if (lane == 63) wtot[12][wave] = incv;
  __syncthreads();
  int base = 0;
  for (int w = 0; w < wave; ++w) base += wtot[12][w];
  int cnt = wtot[12][0] + wtot[12][1] + wtot[12][2] + wtot[12][3];
  if (cnt > CMAX) cnt = CMAX;
  int o = base + incv - cj;
#pragma unroll
  for (int j = 0; j < 32; ++j) {
    if (f[j] > theta) {
      if (o < CMAX) candIdx[o] = t + 256 * j;
      ++o;
    }
  }
  __syncthreads();   // candIdx visible to whole block

  // ================= phase 2: block-wide dynamics (4 chunks of 256) =====
  float cfr[4], khr[4];
  int   idxr[4];
#pragma unroll
  for (int p = 0; p < 4; ++p) {
    cfr[p] = -3.0e38f; khr[p] = -3.0e38f; idxr[p] = 0x7FFFFFFF;
    if (256 * p < cnt) {               // block-uniform chunk skip
      const int ci = t + 256 * p;
      if (ci < cnt) {
        const int n = candIdx[ci];
        const size_t ei = ((size_t)b * ROWN + (size_t)n) * 4 + (size_t)e;
        float sc;
        if (in_f32) sc = ((const float*)scores_raw)[ei];
        else sc = __uint_as_float(((unsigned)((const unsigned short*)scores_raw)[ei]) << 16);
        cfr[p] = sc + gumbel_of(gbase + (unsigned)n);   // bit-exact
        khr[p] = 0.0f;
        idxr[p] = n;
      }
    }
  }

  // 32 np-faithful dynamics iterations; 2 barriers/iter, distinct LDS arrays
  // (write redM / barA / read redM / write redZ / barB / read redZ -> safe).
#pragma unroll 1
  for (int it = 0; it < 32; ++it) {
    float m2 = -3.4e38f;
#pragma unroll
    for (int p = 0; p < 4; ++p)
      if (256 * p < cnt) m2 = fmaxf(m2, cfr[p]);
#pragma unroll
    for (int off = 32; off >= 1; off >>= 1) m2 = fmaxf(m2, __shfl_xor(m2, off));
    if (lane == 0) redM[wave] = m2;
    __syncthreads();
    m2 = fmaxf(fmaxf(redM[0], redM[1]), fmaxf(redM[2], redM[3]));
    const float xm = m2 / 0.1f;

    float ek[4];
    float Z = 0.0f;
#pragma unroll
    for (int p = 0; p < 4; ++p) {
      float ev = 0.0f;
      if (256 * p < cnt) {
        if (cfr[p] - m2 > -10.398f) { ev = expf(cfr[p] / 0.1f - xm); Z += ev; }
      }
      ek[p] = ev;
    }
#pragma unroll
    for (int off = 32; off >= 1; off >>= 1) Z += __shfl_xor(Z, off);
    if (lane == 0) redZ[wave] = Z;
    __syncthreads();
    Z = (redZ[0] + redZ[1]) + (redZ[2] + redZ[3]);   // fixed deterministic order

#pragma unroll
    for (int p = 0; p < 4; ++p) {
      if (256 * p < cnt && ek[p] > 0.0f) {
        const float pp = ek[p] / Z;
        khr[p] += pp;
        const float msk = 1.0f - pp;
        if (msk != 1.0f) cfr[p] += logf(fmaxf(msk, EPS_TINY));
      }
    }
  }

  // top-32 of khot, lowest-n tie-break, block-wide (double-buffered slots)
#pragma unroll 1
  for (int pass = 0; pass < 32; ++pass) {
    float bv = -3.4e38f; int bi = 0x7FFFFFFF;
#pragma unroll
    for (int p = 0; p < 4; ++p) {
      if (256 * p < cnt) {
        const float v = khr[p]; const int ix = idxr[p];
        if (v > bv || (v == bv && ix < bi)) { bv = v; bi = ix; }
      }
    }
#pragma unroll
    for (int off = 32; off >= 1; off >>= 1) {
      const float ov = __shfl_xor(bv, off);
      const int   oi = __shfl_xor(bi, off);
      if (ov > bv || (ov == bv && oi < bi)) { bv = ov; bi = oi; }
    }
    if (lane == 0) { bV[pass & 1][wave] = bv; bI[pass & 1][wave] = bi; }
    __syncthreads();
#pragma unroll
    for (int w = 0; w < 4; ++w) {
      const float ov = bV[pass & 1][w]; const int oi = bI[pass & 1][w];
      if (ov > bv || (ov == bv && oi < bi)) { bv = ov; bi = oi; }
    }
    if (t == 0) sel[pass] = bi;
#pragma unroll
    for (int p = 0; p < 4; ++p)
      if (256 * p < cnt && idxr[p] == bi) khr[p] = -3.0e38f;
  }
  __syncthreads();

  if (t < 32) selws[r * 32 + t] = sel[t];
}

// =====================================================================
// Kernel 2: bitmap expand -> coalesced float4 slab. grid=2048 (4 n-slices
// per (rep,b) group), 256 thr. Pure write-BW bound (~67 MB).
// =====================================================================
__global__ __launch_bounds__(TPB)
void expand_out(const int* __restrict__ selws, float4* __restrict__ out4) {
  const int t   = threadIdx.x;
  const int blk = blockIdx.x;        // 0..2047
  const int grp = blk >> 2;          // rep*256 + b
  const int s   = blk & 3;           // n-slice of 2048
  const int rep = grp >> 8;
  const int b   = grp & 255;

  __shared__ unsigned ebm[4 * 256];  // 4 e-planes x 8192 bits
#pragma unroll
  for (int p = 0; p < 4; ++p) ebm[t + 256 * p] = 0u;
  __syncthreads();
  if (t < 4) {
    const int r = rep * 1024 + b * 4 + t;
#pragma unroll 1
    for (int p = 0; p < 32; ++p) {
      const int ix = selws[r * 32 + p];
      ebm[t * 256 + (ix >> 5)] |= (1u << (ix & 31));
    }
  }
  __syncthreads();

  const size_t obase = (size_t)grp * ROWN;
#pragma unroll
  for (int j = 0; j < 8; ++j) {
    const int n = s * 2048 + t + 256 * j;
    float4 v;
    v.x = ((ebm[0 * 256 + (n >> 5)] >> (n & 31)) & 1u) ? 1.0f : 0.0f;
    v.y = ((ebm[1 * 256 + (n >> 5)] >> (n & 31)) & 1u) ? 1.0f : 0.0f;
    v.z = ((ebm[2 * 256 + (n >> 5)] >> (n & 31)) & 1u) ? 1.0f : 0.0f;
    v.w = ((ebm[3 * 256 + (n >> 5)] >> (n & 31)) & 1u) ? 1.0f : 0.0f;
    out4[obase + (size_t)n] = v;
  }
}

extern "C" void kernel_launch(void* const* d_in, const int* in_sizes, int n_in,
                              void* d_out, int out_size, void* d_ws, size_t ws_size,
                              hipStream_t stream) {
  const void* scores = d_in[0];      // dtype autodetected in-kernel
  int* selws = (int*)d_ws;           // 2048 rows x 32 ints = 256 KB
  topk_row<<<dim3(2048), dim3(TPB), 0, stream>>>(scores, selws);
  expand_out<<<dim3(2048), dim3(TPB), 0, stream>>>(selws, (float4*)d_out);
}